// Round 11
// baseline (701.952 us; speedup 1.0000x reference)
//
#include <hip/hip_runtime.h>
#include <cstdint>
#include <type_traits>

// GNN GATv2 x3 + mean-pool + MLP.
// All GEMMs on fp16 MFMA; fp16 tables; fp16 CSR edge features (self-loop =
// last CSR entry). k2 = 2-wide pipelined edge loop (R7 champion, VGPR36) +
// R11: degree-sorted node permutation (kills the max-vs-mean divergence tail
// inside each wave) + packed-h2 logit reduction (one shfl chain for 2 edges).
constexpr int GNUM = 128;   // graphs
constexpr int DBINS = 64;   // degree-sort bins (Poisson ~17, clamp at 63)

typedef _Float16 h2 __attribute__((ext_vector_type(2)));
typedef _Float16 h4 __attribute__((ext_vector_type(4)));
typedef _Float16 h8 __attribute__((ext_vector_type(8)));
typedef float f4 __attribute__((ext_vector_type(4)));

// ---------------------------------------------------------------- setup kernels

__global__ __launch_bounds__(256) void hist_kernel(const int* __restrict__ dst,
                                                   int* __restrict__ cnt, int E) {
  int i = blockIdx.x * 256 + threadIdx.x;
  if (i < E) atomicAdd(&cnt[dst[i]], 1);
}

// ---- 3-phase parallel exclusive scan of (cnt[i]+1), 512 elems per block ----
// Also LDS-aggregates the degree histogram for the counting sort (R11).
__global__ __launch_bounds__(256) void scan_part_kernel(const int* __restrict__ cnt,
                                                        int* __restrict__ bpart,
                                                        int* __restrict__ deghist, int n) {
  __shared__ int red[256];
  __shared__ int dh[DBINS];
  int base = blockIdx.x * 512;
  int t = threadIdx.x;
  if (t < DBINS) dh[t] = 0;
  __syncthreads();
  int s = 0;
  int i0 = base + t, i1 = base + 256 + t;
  if (i0 < n) { int c = cnt[i0] + 1; s += c; atomicAdd(&dh[c < DBINS - 1 ? c : DBINS - 1], 1); }
  if (i1 < n) { int c = cnt[i1] + 1; s += c; atomicAdd(&dh[c < DBINS - 1 ? c : DBINS - 1], 1); }
  red[t] = s;
  __syncthreads();
  for (int off = 128; off > 0; off >>= 1) {
    if (t < off) red[t] += red[t + off];
    __syncthreads();
  }
  if (t == 0) bpart[blockIdx.x] = red[0];
  if (t < DBINS && dh[t] > 0) atomicAdd(&deghist[t], dh[t]);
}

// scan of block partials + fused graph-boundary search + fused 64-bin degree scan
__global__ __launch_bounds__(1024) void scan_top_kernel(const int* __restrict__ bpart,
                                                        int* __restrict__ boff,
                                                        int* __restrict__ row_ptr,
                                                        const int* __restrict__ batch,
                                                        int* __restrict__ gstart,
                                                        const int* __restrict__ deghist,
                                                        int* __restrict__ degbase,
                                                        int B, int n) {
  __shared__ int buf[1024];
  __shared__ int dsc[DBINS];
  int t = threadIdx.x;
  buf[t] = (t < B) ? bpart[t] : 0;
  __syncthreads();
  for (int off = 1; off < 1024; off <<= 1) {
    int v = (t >= off) ? buf[t - off] : 0;
    __syncthreads();
    buf[t] += v;
    __syncthreads();
  }
  if (t < B) boff[t] = (t == 0) ? 0 : buf[t - 1];
  if (t == 0) row_ptr[n] = buf[1023];
  // fused gbound: graph g's node range start (batch is sorted)
  if (t <= GNUM) {
    int lo = 0, hi = n;
    while (lo < hi) {
      int mid = (lo + hi) >> 1;
      if (batch[mid] < t) lo = mid + 1; else hi = mid;
    }
    gstart[t] = lo;
  }
  // fused: exclusive scan of degree histogram -> degbase
  int myc = 0;
  if (t < DBINS) { myc = deghist[t]; dsc[t] = myc; }
  __syncthreads();
  for (int off = 1; off < DBINS; off <<= 1) {
    int v = (t >= off && t < DBINS) ? dsc[t - off] : 0;
    __syncthreads();
    if (t < DBINS) dsc[t] += v;
    __syncthreads();
  }
  if (t < DBINS) degbase[t] = dsc[t] - myc;
}

__global__ __launch_bounds__(256) void scan_write_kernel(const int* __restrict__ cnt,
                                                         const int* __restrict__ boff,
                                                         int* __restrict__ row_ptr,
                                                         int* __restrict__ fill, int n) {
  __shared__ int red[256];
  int base = blockIdx.x * 512;
  int t = threadIdx.x;
  int i0 = base + 2 * t, i1 = base + 2 * t + 1;
  int v0 = (i0 < n) ? cnt[i0] + 1 : 0;
  int v1 = (i1 < n) ? cnt[i1] + 1 : 0;
  int val = v0 + v1;
  red[t] = val;
  __syncthreads();
  for (int off = 1; off < 256; off <<= 1) {
    int u = (t >= off) ? red[t - off] : 0;
    __syncthreads();
    red[t] += u;
    __syncthreads();
  }
  int o = boff[blockIdx.x] + red[t] - val;   // exclusive prefix for this pair
  if (i0 < n) { row_ptr[i0] = o; fill[i0] = o; }
  if (i1 < n) { row_ptr[i1] = o + v0; fill[i1] = o + v0; }
}

// counting-sort scatter: perm = node ids ordered by segment length (R11).
__global__ __launch_bounds__(256) void permute_kernel(const int* __restrict__ cnt,
                                                      int* __restrict__ degbase,
                                                      int* __restrict__ perm, int n) {
  __shared__ int lcnt[DBINS];
  __shared__ int lbase[DBINS];
  int t = threadIdx.x;
  if (t < DBINS) lcnt[t] = 0;
  __syncthreads();
  int i = blockIdx.x * 256 + t;
  int bin = 0, lr = 0;
  if (i < n) {
    int c = cnt[i] + 1;
    bin = c < DBINS - 1 ? c : DBINS - 1;
    lr = atomicAdd(&lcnt[bin], 1);
  }
  __syncthreads();
  if (t < DBINS && lcnt[t] > 0) lbase[t] = atomicAdd(&degbase[t], lcnt[t]);
  __syncthreads();
  if (i < n) perm[lbase[bin] + lr] = i;
}

// scatter edges into CSR slots; write fp16 edge features directly in CSR order
__global__ __launch_bounds__(256) void scatter_kernel(const int* __restrict__ src,
                                                      const int* __restrict__ dst,
                                                      const float* __restrict__ ea,
                                                      int* __restrict__ fill,
                                                      int* __restrict__ csr_src,
                                                      _Float16* __restrict__ ea_csr, int E) {
  int i = blockIdx.x * 256 + threadIdx.x;
  if (i >= E) return;
  int d = dst[i];
  int p = atomicAdd(&fill[d], 1);
  csr_src[p] = src[i];
  float4 e0 = *(const float4*)&ea[(size_t)i * 8];
  float4 e1 = *(const float4*)&ea[(size_t)i * 8 + 4];
  h8 v;
  v[0] = (_Float16)e0.x; v[1] = (_Float16)e0.y; v[2] = (_Float16)e0.z; v[3] = (_Float16)e0.w;
  v[4] = (_Float16)e1.x; v[5] = (_Float16)e1.y; v[6] = (_Float16)e1.z; v[7] = (_Float16)e1.w;
  *(h8*)&ea_csr[(size_t)p * 8] = v;
}

// fill self-loop slot (last of each segment) with segment-mean attrs.
// 8 threads per node (one per edge channel).
__global__ __launch_bounds__(256) void selfloop_kernel(const int* __restrict__ row_ptr,
                                                       int* __restrict__ csr_src,
                                                       _Float16* __restrict__ ea_csr, int n) {
  int idx = blockIdx.x * 256 + threadIdx.x;
  int i = idx >> 3, c = idx & 7;
  if (i >= n) return;
  int s = row_ptr[i], e = row_ptr[i + 1] - 1;   // [s,e) real edges, e = self slot
  float a = 0.f;
  for (int j = s; j < e; j++) a += (float)ea_csr[(size_t)j * 8 + c];
  float inv = 1.f / fmaxf((float)(e - s), 1.f);
  ea_csr[(size_t)e * 8 + c] = (_Float16)(a * inv);
  if (c == 0) csr_src[e] = i;
}

// pack all 6 weight matrices f32 -> fp16 MFMA B-fragment order in one launch.
__global__ __launch_bounds__(256) void pack_all_kernel(
    const float* __restrict__ wl1, _Float16* __restrict__ p1l,
    const float* __restrict__ wr1, _Float16* __restrict__ p1r,
    const float* __restrict__ wl2, _Float16* __restrict__ p2l,
    const float* __restrict__ wr2, _Float16* __restrict__ p2r,
    const float* __restrict__ wl3, _Float16* __restrict__ p3l,
    const float* __restrict__ wr3, _Float16* __restrict__ p3r) {
  int y = blockIdx.y;
  const float* w; _Float16* wp; int Kreal, Kpad, NC;
  switch (y) {
    case 0: w = wl1; wp = p1l; Kreal = 16;  Kpad = 32;  NC = 128; break;
    case 1: w = wr1; wp = p1r; Kreal = 16;  Kpad = 32;  NC = 128; break;
    case 2: w = wl2; wp = p2l; Kreal = 128; Kpad = 128; NC = 128; break;
    case 3: w = wr2; wp = p2r; Kreal = 128; Kpad = 128; NC = 128; break;
    case 4: w = wl3; wp = p3l; Kreal = 128; Kpad = 128; NC = 32;  break;
    default: w = wr3; wp = p3r; Kreal = 128; Kpad = 128; NC = 32; break;
  }
  int KB = Kpad / 32;
  int total = (NC / 16) * KB * 64;
  int idx = blockIdx.x * 256 + threadIdx.x;
  if (idx >= total) return;
  int lane = idx & 63;
  int blk = idx >> 6;
  int nt = blk / KB, kb = blk % KB;
  int col = nt * 16 + (lane & 15);
  int krow = kb * 32 + (lane >> 4) * 8;
  h8 v;
#pragma unroll
  for (int j = 0; j < 8; j++)
    v[j] = (krow + j < Kreal) ? (_Float16)w[(size_t)(krow + j) * NC + col] : (_Float16)0.f;
  *(h8*)&wp[(size_t)idx * 8] = v;
}

// ---------------------------------------------------------------- node transform GEMMs

// fp16 MFMA, K=128. 256 thr = 4 waves, 16 nodes/wave, 64 nodes/block.
template <int K, int NCOLS>
__global__ __launch_bounds__(256) void k1m_kernel(const _Float16* __restrict__ x,
                                                  const _Float16* __restrict__ wp0,
                                                  const float* __restrict__ b0,
                                                  _Float16* __restrict__ out0,
                                                  const _Float16* __restrict__ wp1,
                                                  const float* __restrict__ b1,
                                                  _Float16* __restrict__ out1, int n) {
  constexpr int NT = NCOLS / 16, KB = K / 32;
  const _Float16* wp = blockIdx.y ? wp1 : wp0;
  const float* b = blockIdx.y ? b1 : b0;
  _Float16* out = blockIdx.y ? out1 : out0;

  int tid = threadIdx.x;
  int wave = tid >> 6, lane = tid & 63;
  int m = lane & 15, quad = lane >> 4;
  int node0 = blockIdx.x * 64 + wave * 16;

  h8 afrag[KB];
  int anode = node0 + m;
  if (anode < n) {
#pragma unroll
    for (int kb = 0; kb < KB; kb++)
      afrag[kb] = *(const h8*)&x[(size_t)anode * K + kb * 32 + quad * 8];
  } else {
#pragma unroll
    for (int kb = 0; kb < KB; kb++) afrag[kb] = (h8)(_Float16)0.f;
  }

  f4 acc[NT] = {};
#pragma unroll
  for (int nt = 0; nt < NT; nt++) {
#pragma unroll
    for (int kb = 0; kb < KB; kb++) {
      h8 bfrag = *(const h8*)&wp[((size_t)(nt * KB + kb) * 64 + lane) * 8];
      acc[nt] = __builtin_amdgcn_mfma_f32_16x16x32_f16(afrag[kb], bfrag, acc[nt], 0, 0, 0);
    }
  }

#pragma unroll
  for (int nt = 0; nt < NT; nt++) {
#pragma unroll
    for (int r = 0; r < 4; r++) {
      int row = node0 + quad * 4 + r;
      if (row < n) {
        int col = nt * 16 + m;
        out[(size_t)row * NCOLS + col] = (_Float16)(acc[nt][r] + b[col]);
      }
    }
  }
}

// fp16 MFMA, Kreal=16 zero-padded to 32 (layer 1); reads f32 x directly.
template <int NCOLS>
__global__ __launch_bounds__(256) void k1m16_kernel(const float* __restrict__ x,
                                                    const _Float16* __restrict__ wp0,
                                                    const float* __restrict__ b0,
                                                    _Float16* __restrict__ out0,
                                                    const _Float16* __restrict__ wp1,
                                                    const float* __restrict__ b1,
                                                    _Float16* __restrict__ out1, int n) {
  constexpr int NT = NCOLS / 16;
  const _Float16* wp = blockIdx.y ? wp1 : wp0;
  const float* b = blockIdx.y ? b1 : b0;
  _Float16* out = blockIdx.y ? out1 : out0;

  int tid = threadIdx.x;
  int wave = tid >> 6, lane = tid & 63;
  int m = lane & 15, quad = lane >> 4;
  int node0 = blockIdx.x * 64 + wave * 16;

  int anode = node0 + m;
  h8 afrag = (h8)(_Float16)0.f;
  if (anode < n && quad < 2) {
    float4 v0 = *(const float4*)&x[(size_t)anode * 16 + quad * 8];
    float4 v1 = *(const float4*)&x[(size_t)anode * 16 + quad * 8 + 4];
    afrag[0] = (_Float16)v0.x; afrag[1] = (_Float16)v0.y;
    afrag[2] = (_Float16)v0.z; afrag[3] = (_Float16)v0.w;
    afrag[4] = (_Float16)v1.x; afrag[5] = (_Float16)v1.y;
    afrag[6] = (_Float16)v1.z; afrag[7] = (_Float16)v1.w;
  }

  f4 acc[NT] = {};
#pragma unroll
  for (int nt = 0; nt < NT; nt++) {
    h8 bfrag = *(const h8*)&wp[((size_t)nt * 64 + lane) * 8];
    acc[nt] = __builtin_amdgcn_mfma_f32_16x16x32_f16(afrag, bfrag, acc[nt], 0, 0, 0);
  }

#pragma unroll
  for (int nt = 0; nt < NT; nt++) {
#pragma unroll
    for (int r = 0; r < 4; r++) {
      int row = node0 + quad * 4 + r;
      if (row < n) {
        int col = nt * 16 + m;
        out[(size_t)row * NCOLS + col] = (_Float16)(acc[nt][r] + b[col]);
      }
    }
  }
}

// ---------------------------------------------------------------- fused GATv2 edge+softmax+aggregate
// One-pass softmax (no max-shift; logits O(1)). Self-loop is a normal CSR entry.
// Packed-fp16 logit math; att pre-scaled by log2(e). 2-edge software pipeline.
// R11: nodes visited via degree-sorted perm (equal lengths per wave); both
// edges' logit parts packed in one h2 -> single shfl/pk_add reduce chain.
template <int H>
__global__ __launch_bounds__(128) void k2_kernel(
    const _Float16* __restrict__ xl, const _Float16* __restrict__ xr,
    const int* __restrict__ row_ptr, const int* __restrict__ csr_src,
    const _Float16* __restrict__ ea_csr, const int* __restrict__ perm,
    const float* __restrict__ we, const float* __restrict__ att,
    const float* __restrict__ bc, _Float16* __restrict__ out, int n) {
  constexpr int HC = H * 32;
  constexpr int NL = HC / 4;   // lanes per node (32 or 8)
  constexpr int NPB = 128 / NL;

  int tid = threadIdx.x;
  int ln = tid / NL, q = tid % NL;
  int c0 = 4 * q;
  int nidx = blockIdx.x * NPB + ln;
  if (nidx >= n) return;
  int node = perm[nidx];

  h2 w2[8][2];
#pragma unroll
  for (int k = 0; k < 8; k++) {
    float4 v = *(const float4*)&we[k * HC + c0];
    w2[k][0] = h2{(_Float16)v.x, (_Float16)v.y};
    w2[k][1] = h2{(_Float16)v.z, (_Float16)v.w};
  }
  const float LOG2E = 1.44269504088896f;
  float4 av = *(const float4*)&att[c0];
  h2 a0 = h2{(_Float16)(av.x * LOG2E), (_Float16)(av.y * LOG2E)};
  h2 a1 = h2{(_Float16)(av.z * LOG2E), (_Float16)(av.w * LOG2E)};
  h4 xrh = *(const h4*)&xr[(size_t)node * HC + c0];
  h2 xr0 = h2{xrh[0], xrh[1]}, xr1 = h2{xrh[2], xrh[3]};
  const h2 p2 = h2{(_Float16)0.2f, (_Float16)0.2f};

  float acc[4] = {0.f, 0.f, 0.f, 0.f};
  float s = 0.f;

  int start = row_ptr[node], end = row_ptr[node + 1];   // len >= 1 (self loop)
  int len = end - start;
  int pairs = (len + 1) >> 1;

  // prologue: load pair 0 (clamped)
  int j1 = (start + 1 < end) ? start + 1 : start;
  float m1 = (start + 1 < end) ? 1.f : 0.f;
  int s0 = csr_src[start], s1 = csr_src[j1];
  h8 e0 = *(const h8*)&ea_csr[(size_t)start * 8];
  h8 e1 = *(const h8*)&ea_csr[(size_t)j1 * 8];
  h4 x0 = *(const h4*)&xl[(size_t)s0 * HC + c0];
  h4 x1 = *(const h4*)&xl[(size_t)s1 * HC + c0];

#pragma unroll 2
  for (int p = 0; p < pairs; p++) {
    // ---- issue next pair's src/ea loads (clamped; unused garbage on last) ----
    int jn = start + 2 * (p + 1);
    int k0 = (jn < end) ? jn : start;
    int k1 = (jn + 1 < end) ? jn + 1 : k0;
    float nm1 = (jn + 1 < end) ? 1.f : 0.f;
    int ns0 = csr_src[k0], ns1 = csr_src[k1];
    h8 ne0 = *(const h8*)&ea_csr[(size_t)k0 * 8];
    h8 ne1 = *(const h8*)&ea_csr[(size_t)k1 * 8];

    // ---- logits for current pair (two independent chains) ----
    h2 t00 = h2{x0[0], x0[1]} + xr0;
    h2 t01 = h2{x0[2], x0[3]} + xr1;
    h2 t10 = h2{x1[0], x1[1]} + xr0;
    h2 t11 = h2{x1[2], x1[3]} + xr1;
#pragma unroll
    for (int k = 0; k < 8; k++) {
      h2 ev0 = h2{e0[k], e0[k]};
      h2 ev1 = h2{e1[k], e1[k]};
      t00 += ev0 * w2[k][0];
      t01 += ev0 * w2[k][1];
      t10 += ev1 * w2[k][0];
      t11 += ev1 * w2[k][1];
    }
    t00 = __builtin_elementwise_max(t00, t00 * p2);
    t01 = __builtin_elementwise_max(t01, t01 * p2);
    t10 = __builtin_elementwise_max(t10, t10 * p2);
    t11 = __builtin_elementwise_max(t11, t11 * p2);
    h2 pd0 = t00 * a0 + t01 * a1;
    h2 pd1 = t10 * a0 + t11 * a1;
    // pack both edges' parts into one h2, reduce with one shfl chain
    h2 pp = h2{(_Float16)(pd0[0] + pd0[1]), (_Float16)(pd1[0] + pd1[1])};

    // ---- issue next pair's xl gathers before the reduce chain ----
    h4 nx0 = *(const h4*)&xl[(size_t)ns0 * HC + c0];
    h4 nx1 = *(const h4*)&xl[(size_t)ns1 * HC + c0];

    // ---- reduce across the 8 lanes of each head (packed), exp, accumulate ----
#pragma unroll
    for (int mseg = 1; mseg <= 4; mseg <<= 1) {
      int pv = __shfl_xor(__builtin_bit_cast(int, pp), mseg, 64);
      pp += __builtin_bit_cast(h2, pv);
    }
    float pe0 = __builtin_amdgcn_exp2f((float)pp[0]);
    float pe1 = __builtin_amdgcn_exp2f((float)pp[1]) * m1;
    s += pe0 + pe1;
#pragma unroll
    for (int i = 0; i < 4; i++)
      acc[i] += pe0 * (float)x0[i] + pe1 * (float)x1[i];

    // ---- rotate pipeline registers ----
    s0 = ns0; s1 = ns1; e0 = ne0; e1 = ne1; x0 = nx0; x1 = nx1; m1 = nm1;
  }

  float inv = 1.f / (s + 1e-16f);
  h4 o;
#pragma unroll
  for (int i = 0; i < 4; i++) {
    float v = acc[i] * inv + bc[c0 + i];
    o[i] = (_Float16)(v > 0.f ? v : (__expf(v) - 1.f));   // elu
  }
  *(h4*)&out[(size_t)node * HC + c0] = o;
}

// ---------------------------------------------------------------- fused pooling + MLP
__global__ __launch_bounds__(256) void poolfc_kernel(const _Float16* __restrict__ h,
                                                     const int* __restrict__ gstart,
                                                     const float* __restrict__ w1,
                                                     const float* __restrict__ b1,
                                                     const float* __restrict__ w2,
                                                     const float* __restrict__ b2,
                                                     float* __restrict__ out) {
  __shared__ float red[256];
  __shared__ float g[32];
  __shared__ float a1[64];
  int gi = blockIdx.x;
  int t = threadIdx.x;
  int s = gstart[gi], e = gstart[gi + 1];
  int c = t & 31, rg = t >> 5;
  float acc = 0.f;
  for (int i = s + rg; i < e; i += 8) acc += (float)h[(size_t)i * 32 + c];
  red[t] = acc;
  __syncthreads();
  if (t < 128) red[t] += red[t + 128];
  __syncthreads();
  if (t < 64) red[t] += red[t + 64];
  __syncthreads();
  if (t < 32) g[t] = (red[t] + red[t + 32]) / fmaxf((float)(e - s), 1.f);
  __syncthreads();
  if (t < 64) {
    float v = b1[t];
    for (int k = 0; k < 32; k++) v += g[k] * w1[k * 64 + t];
    a1[t] = v > 0.f ? v : (__expf(v) - 1.f);
  }
  __syncthreads();
  if (t < 4) {
    float o = b2[t];
    for (int k = 0; k < 64; k++) o += a1[k] * w2[k * 4 + t];
    out[gi * 4 + t] = o;
  }
}

// ---------------------------------------------------------------- launch

extern "C" void kernel_launch(void* const* d_in, const int* in_sizes, int n_in,
                              void* d_out, int out_size, void* d_ws, size_t ws_size,
                              hipStream_t stream) {
  const float* x     = (const float*)d_in[0];
  const int*   ei    = (const int*)d_in[1];
  const float* eattr = (const float*)d_in[2];
  const int*   batch = (const int*)d_in[3];
  const float *wl1 = (const float*)d_in[4],  *bl1 = (const float*)d_in[5];
  const float *wr1 = (const float*)d_in[6],  *br1 = (const float*)d_in[7];
  const float *we1 = (const float*)d_in[8],  *at1 = (const float*)d_in[9];
  const float *bc1 = (const float*)d_in[10];
  const float *wl2 = (const float*)d_in[11], *bl2 = (const float*)d_in[12];
  const float *wr2 = (const float*)d_in[13], *br2 = (const float*)d_in[14];
  const float *we2 = (const float*)d_in[15], *at2 = (const float*)d_in[16];
  const float *bc2 = (const float*)d_in[17];
  const float *wl3 = (const float*)d_in[18], *bl3 = (const float*)d_in[19];
  const float *wr3 = (const float*)d_in[20], *br3 = (const float*)d_in[21];
  const float *we3 = (const float*)d_in[22], *at3 = (const float*)d_in[23];
  const float *bc3 = (const float*)d_in[24];
  const float *wf1 = (const float*)d_in[25], *bf1 = (const float*)d_in[26];
  const float *wf2 = (const float*)d_in[27], *bf2 = (const float*)d_in[28];

  int N = in_sizes[0] / 16;
  int E = in_sizes[1] / 2;
  const int* srcp = ei;
  const int* dstp = ei + E;
  int EA = E + N;             // CSR entries incl. self-loops
  int NB = (N + 511) / 512;   // scan blocks (<=1024)

  char* wsb = (char*)d_ws;
  size_t off = 0;
  auto alloc = [&](size_t bytes) -> char* {
    char* p = wsb + off;
    off += (bytes + 255) & ~(size_t)255;
    return p;
  };
  // cnt + deghist + degbase contiguous so one memset covers all three
  int*       cnt     = (int*)alloc((size_t)N * 4 + 2 * DBINS * 4);
  int*       deghist = cnt + N;
  int*       degbase = cnt + N + DBINS;
  int*       row_ptr = (int*)alloc((size_t)(N + 1) * 4);
  int*       fill    = (int*)alloc((size_t)N * 4);
  int*       bpart   = (int*)alloc((size_t)1024 * 4);
  int*       boff    = (int*)alloc((size_t)1024 * 4);
  int*       perm    = (int*)alloc((size_t)N * 4);
  int*       csr_src = (int*)alloc((size_t)EA * 4);
  _Float16*  ea_csr  = (_Float16*)alloc((size_t)EA * 8 * 2);
  _Float16*  xl      = (_Float16*)alloc((size_t)N * 128 * 2);
  _Float16*  xr      = (_Float16*)alloc((size_t)N * 128 * 2);
  _Float16*  h16     = (_Float16*)alloc((size_t)N * 128 * 2);
  _Float16*  h3      = (_Float16*)alloc((size_t)N * 32 * 2);
  int*       gstart  = (int*)alloc((size_t)(GNUM + 1) * 4);
  _Float16*  wp1l    = (_Float16*)alloc((size_t)32 * 128 * 2);
  _Float16*  wp1r    = (_Float16*)alloc((size_t)32 * 128 * 2);
  _Float16*  wp2l    = (_Float16*)alloc((size_t)128 * 128 * 2);
  _Float16*  wp2r    = (_Float16*)alloc((size_t)128 * 128 * 2);
  _Float16*  wp3l    = (_Float16*)alloc((size_t)128 * 32 * 2);
  _Float16*  wp3r    = (_Float16*)alloc((size_t)128 * 32 * 2);

  hipMemsetAsync(cnt, 0, (size_t)N * 4 + 2 * DBINS * 4, stream);

  hist_kernel<<<(E + 255) / 256, 256, 0, stream>>>(dstp, cnt, E);
  scan_part_kernel<<<NB, 256, 0, stream>>>(cnt, bpart, deghist, N);
  scan_top_kernel<<<1, 1024, 0, stream>>>(bpart, boff, row_ptr, batch, gstart,
                                          deghist, degbase, NB, N);
  scan_write_kernel<<<NB, 256, 0, stream>>>(cnt, boff, row_ptr, fill, N);
  permute_kernel<<<(N + 255) / 256, 256, 0, stream>>>(cnt, degbase, perm, N);
  scatter_kernel<<<(E + 255) / 256, 256, 0, stream>>>(srcp, dstp, eattr, fill, csr_src, ea_csr, E);
  selfloop_kernel<<<(N * 8 + 255) / 256, 256, 0, stream>>>(row_ptr, csr_src, ea_csr, N);
  pack_all_kernel<<<dim3(8, 6), 256, 0, stream>>>(wl1, wp1l, wr1, wp1r,
                                                  wl2, wp2l, wr2, wp2r,
                                                  wl3, wp3l, wr3, wp3r);

  // layer 1: K=16 -> 128 (fp16 MFMA, K zero-padded to 32, f32 input)
  k1m16_kernel<128><<<dim3((N + 63) / 64, 2), 256, 0, stream>>>(
      x, wp1l, bl1, xl, wp1r, br1, xr, N);
  k2_kernel<4><<<(N + 3) / 4, 128, 0, stream>>>(xl, xr, row_ptr, csr_src, ea_csr,
                                                perm, we1, at1, bc1, h16, N);
  // layer 2: K=128 -> 128 (fp16 MFMA)
  k1m_kernel<128, 128><<<dim3((N + 63) / 64, 2), 256, 0, stream>>>(
      h16, wp2l, bl2, xl, wp2r, br2, xr, N);
  k2_kernel<4><<<(N + 3) / 4, 128, 0, stream>>>(xl, xr, row_ptr, csr_src, ea_csr,
                                                perm, we2, at2, bc2, h16, N);
  // layer 3: K=128 -> 32 (fp16 MFMA, single head)
  k1m_kernel<128, 32><<<dim3((N + 63) / 64, 2), 256, 0, stream>>>(
      h16, wp3l, bl3, xl, wp3r, br3, xr, N);
  k2_kernel<1><<<(N + 15) / 16, 128, 0, stream>>>(xl, xr, row_ptr, csr_src, ea_csr,
                                                  perm, we3, at3, bc3, h3, N);

  poolfc_kernel<<<GNUM, 256, 0, stream>>>(h3, gstart, wf1, bf1, wf2, bf2, (float*)d_out);
}